// Round 1
// baseline (2092.269 us; speedup 1.0000x reference)
//
#include <hip/hip_runtime.h>

// LNN_50302656971188 — batched grad + partial-Hessian of 2-layer softmax MLP + 2x2 solve.
// Strategy: per row, 1 forward + 1 backward + 2 HVPs (tangents = W1[:,2], W1[:,3]).
// All heavy work = 6 matvecs vs W2 (128x128) per row. fp32 vector ALU (no fp32 MFMA).
// Layout: wave owns 8 rows; lane owns channels {l, l+64}. W2 in LDS twice
// (forward-pack and transpose-pack) so all W2 reads are contiguous ds_read_b128.

#define RPW 8        // rows per wave per iteration
#define NWAVES 4
#define NTHREADS 256
#define NGRID 512
#define NITERS 16    // rows/block = NITERS*NWAVES*RPW = 512 ; 512 blocks * 512 = 262144
#define LDS_FLOATS (16384 + 16384 + NWAVES * RPW * 128)   // 147456 B

__device__ __forceinline__ float wred64(float v) {
#pragma unroll
    for (int m = 1; m < 64; m <<= 1) v += __shfl_xor(v, m, 64);
    return v;
}

__device__ __forceinline__ void matvec8(const float* W, const float* Srow,
                                        int cA4, int cB4,
                                        float (&za)[RPW], float (&zb)[RPW])
{
#pragma unroll 4
    for (int j4 = 0; j4 < 32; ++j4) {
        const float4 wA = *(const float4*)(W + (j4 << 9) + cA4);
        const float4 wB = *(const float4*)(W + (j4 << 9) + cB4);
#pragma unroll
        for (int r = 0; r < RPW; ++r) {
            const float4 s4 = *(const float4*)(Srow + r * 128 + (j4 << 2));
            za[r] = fmaf(wA.x, s4.x, fmaf(wA.y, s4.y, fmaf(wA.z, s4.z, fmaf(wA.w, s4.w, za[r]))));
            zb[r] = fmaf(wB.x, s4.x, fmaf(wB.y, s4.y, fmaf(wB.z, s4.z, fmaf(wB.w, s4.w, zb[r]))));
        }
    }
}

extern "C" __global__ __launch_bounds__(NTHREADS, 1)
void lnn_kernel(const float* __restrict__ gx, const float* __restrict__ gW1,
                const float* __restrict__ gb1, const float* __restrict__ gW2,
                const float* __restrict__ gb2, const float* __restrict__ gW3,
                float* __restrict__ gout)
{
    extern __shared__ float lds[];
    float* W2f = lds;            // [32][128][4]: (j>>2, i, j&3) — forward (rows of W2 along j, b128)
    float* W2b = lds + 16384;    // [32][128][4]: (i>>2, j, i&3) — transpose (cols of W2 along i, b128)
    float* Sst = lds + 32768;    // [NWAVES][RPW][128] staging (p / u / pdot / udot, reused)

    const int tid  = threadIdx.x;
    const int lane = tid & 63;
    const int wv   = tid >> 6;
    const int cA = lane, cB = lane + 64;
    const int cA4 = cA << 2, cB4 = cB << 2;

    for (int e = tid; e < 16384; e += NTHREADS) {
        const int i = e >> 7, j = e & 127;
        const float w = gW2[e];
        W2f[((j >> 2) << 9) + (i << 2) + (j & 3)] = w;
        W2b[((i >> 2) << 9) + (j << 2) + (i & 3)] = w;
    }

    const float w1a0 = gW1[cA * 4 + 0], w1a1 = gW1[cA * 4 + 1],
                w1a2 = gW1[cA * 4 + 2], w1a3 = gW1[cA * 4 + 3];
    const float w1b0 = gW1[cB * 4 + 0], w1b1 = gW1[cB * 4 + 1],
                w1b2 = gW1[cB * 4 + 2], w1b3 = gW1[cB * 4 + 3];
    const float b1a = gb1[cA], b1b = gb1[cB];
    const float b2a = gb2[cA], b2b = gb2[cB];
    const float w3a = gW3[cA], w3b = gW3[cB];

    __syncthreads();   // W2 staged; staging buffer below is wave-private (no more barriers)

    float* Srow = Sst + wv * (RPW * 128);

#pragma unroll 1
    for (int it = 0; it < NITERS; ++it) {
        const int row0 = blockIdx.x * (NITERS * NWAVES * RPW) + it * (NWAVES * RPW) + wv * RPW;

        float p0[RPW], p1[RPW], q0[RPW], q1[RPW], v0[RPW], v1[RPW];
        float sw[RPW], pv[RPW], g0[RPW], X2[RPW], X3[RPW];

        // ---- layer 1 forward: p = softmax(W1 x + b1)
#pragma unroll
        for (int r = 0; r < RPW; ++r) {
            const float4 xr = ((const float4*)gx)[row0 + r];
            X2[r] = xr.z; X3[r] = xr.w;
            const float z1a = fmaf(w1a0, xr.x, fmaf(w1a1, xr.y, fmaf(w1a2, xr.z, fmaf(w1a3, xr.w, b1a))));
            const float z1b = fmaf(w1b0, xr.x, fmaf(w1b1, xr.y, fmaf(w1b2, xr.z, fmaf(w1b3, xr.w, b1b))));
            const float ea = __expf(z1a), eb = __expf(z1b);
            const float rs = 1.0f / wred64(ea + eb);
            p0[r] = ea * rs; p1[r] = eb * rs;
            Srow[r * 128 + cA] = p0[r];
            Srow[r * 128 + cB] = p1[r];
        }

        // ---- layer 2 forward: q = softmax(W2 p + b2); u = dL/dz2 = q*(w3 - s)
        float za[RPW], zb[RPW];
#pragma unroll
        for (int r = 0; r < RPW; ++r) { za[r] = b2a; zb[r] = b2b; }
        matvec8(W2f, Srow, cA4, cB4, za, zb);
#pragma unroll
        for (int r = 0; r < RPW; ++r) {
            const float ea = __expf(za[r]), eb = __expf(zb[r]);
            const float rs = 1.0f / wred64(ea + eb);
            q0[r] = ea * rs; q1[r] = eb * rs;
            sw[r] = wred64(fmaf(w3a, q0[r], w3b * q1[r]));
            Srow[r * 128 + cA] = q0[r] * (w3a - sw[r]);
            Srow[r * 128 + cB] = q1[r] * (w3b - sw[r]);
        }

        // ---- backward: v = W2^T u ; gamma = p*(v - p.v) ; g0 = W1[:,0].gamma
#pragma unroll
        for (int r = 0; r < RPW; ++r) { za[r] = 0.f; zb[r] = 0.f; }
        matvec8(W2b, Srow, cA4, cB4, za, zb);
#pragma unroll
        for (int r = 0; r < RPW; ++r) {
            v0[r] = za[r]; v1[r] = zb[r];
            pv[r] = wred64(fmaf(p0[r], v0[r], p1[r] * v1[r]));
            g0[r] = wred64(fmaf(w1a0, p0[r] * (v0[r] - pv[r]), w1b0 * (p1[r] * (v1[r] - pv[r]))));
        }

        float h20[RPW], h21[RPW], h22[RPW], h23[RPW];
        float h30[RPW], h31[RPW], h32[RPW], h33[RPW];

        // ---- HVP with tangent t = W1[:,k] (per-lane: ta = W1[cA,k], tb = W1[cB,k])
        auto hvp = [&](float ta, float tb, float (&o0)[RPW], float (&o1)[RPW],
                       float (&o2)[RPW], float (&o3)[RPW]) {
            float pd0[RPW], pd1[RPW];
#pragma unroll
            for (int r = 0; r < RPW; ++r) {
                const float pi = wred64(fmaf(ta, p0[r], tb * p1[r]));
                pd0[r] = p0[r] * (ta - pi);
                pd1[r] = p1[r] * (tb - pi);
                Srow[r * 128 + cA] = pd0[r];
                Srow[r * 128 + cB] = pd1[r];
            }
            float zd0[RPW], zd1[RPW];
#pragma unroll
            for (int r = 0; r < RPW; ++r) { zd0[r] = 0.f; zd1[r] = 0.f; }
            matvec8(W2f, Srow, cA4, cB4, zd0, zd1);     // zdot2 = W2 pdot
#pragma unroll
            for (int r = 0; r < RPW; ++r) {
                const float sg = wred64(fmaf(q0[r], zd0[r], q1[r] * zd1[r]));
                const float qd0 = q0[r] * (zd0[r] - sg);
                const float qd1 = q1[r] * (zd1[r] - sg);
                const float sd = wred64(fmaf(w3a, qd0, w3b * qd1));
                Srow[r * 128 + cA] = fmaf(qd0, w3a - sw[r], -(q0[r] * sd));  // udot
                Srow[r * 128 + cB] = fmaf(qd1, w3b - sw[r], -(q1[r] * sd));
            }
            float vd0[RPW], vd1[RPW];
#pragma unroll
            for (int r = 0; r < RPW; ++r) { vd0[r] = 0.f; vd1[r] = 0.f; }
            matvec8(W2b, Srow, cA4, cB4, vd0, vd1);     // vdot = W2^T udot
#pragma unroll
            for (int r = 0; r < RPW; ++r) {
                const float dpv = wred64(fmaf(pd0[r], v0[r],
                                     fmaf(pd1[r], v1[r],
                                     fmaf(p0[r], vd0[r], p1[r] * vd1[r]))));
                const float gd0 = fmaf(pd0[r], v0[r] - pv[r], p0[r] * (vd0[r] - dpv));
                const float gd1 = fmaf(pd1[r], v1[r] - pv[r], p1[r] * (vd1[r] - dpv));
                o0[r] = wred64(fmaf(w1a0, gd0, w1b0 * gd1));
                o1[r] = wred64(fmaf(w1a1, gd0, w1b1 * gd1));
                o2[r] = wred64(fmaf(w1a2, gd0, w1b2 * gd1));
                o3[r] = wred64(fmaf(w1a3, gd0, w1b3 * gd1));
            }
        };

        hvp(w1a2, w1b2, h20, h21, h22, h23);   // H[:,2]
        hvp(w1a3, w1b3, h30, h31, h32, h33);   // H[:,3]

        // ---- 2x2 solve + store (tqt passthrough is exact)
#pragma unroll
        for (int r = 0; r < RPW; ++r) {
            const float rhs0 = g0[r] - fmaf(h20[r], X2[r], h21[r] * X3[r]);  // H[2,0],H[2,1]
            const float rhs1 = g0[r] - fmaf(h30[r], X2[r], h31[r] * X3[r]);  // H[3,0],H[3,1]
            const float a = h22[r], b = h32[r], c = h23[r], d = h33[r];      // H22,H23,H32,H33
            const float det = fmaf(a, d, -(b * c));
            const float t0 = fmaf(d, rhs0, -(b * rhs1)) / det;
            const float t1 = fmaf(a, rhs1, -(c * rhs0)) / det;
            if (lane == 0) {
                ((float4*)gout)[row0 + r] = make_float4(X2[r], X3[r], t0, t1);
            }
        }
    }
}

extern "C" void kernel_launch(void* const* d_in, const int* in_sizes, int n_in,
                              void* d_out, int out_size, void* d_ws, size_t ws_size,
                              hipStream_t stream)
{
    const float* gx  = (const float*)d_in[0];
    const float* gW1 = (const float*)d_in[1];
    const float* gb1 = (const float*)d_in[2];
    const float* gW2 = (const float*)d_in[3];
    const float* gb2 = (const float*)d_in[4];
    const float* gW3 = (const float*)d_in[5];
    // d_in[6] = b3: unused (only derivatives of L are needed)
    float* gout = (float*)d_out;

    const size_t shmem = LDS_FLOATS * sizeof(float);   // 147456 B > 64 KB: opt-in
    (void)hipFuncSetAttribute((const void*)lnn_kernel,
                              hipFuncAttributeMaxDynamicSharedMemorySize, (int)shmem);
    lnn_kernel<<<NGRID, NTHREADS, shmem, stream>>>(gx, gW1, gb1, gW2, gb2, gW3, gout);
}

// Round 2
// 1514.527 us; speedup vs baseline: 1.3815x; 1.3815x over previous
//
#include <hip/hip_runtime.h>

// LNN_50302656971188 — batched grad + partial-Hessian of 2-layer softmax MLP + 2x2 solve.
// R2: occupancy 4->8 waves/CU (512-thread block), single stride-129 W2 copy in LDS
// (conflict-free b32 in BOTH row and column direction), LDS 147KB -> 98.8KB.
// Per row: 1 forward + 1 backward + 2 HVPs (tangents W1[:,2], W1[:,3]) = 6 matvecs vs W2.

#define RPW 8        // rows per wave per iteration
#define NWAVES 8
#define NTHREADS 512
#define NGRID 256
#define NITERS 16    // rows/block = NITERS*NWAVES*RPW = 1024 ; 256 blocks * 1024 = 262144
#define LDW2 129     // W2 LDS leading dim: bank=(i+j)%32 -> 2-way (free) both directions
#define LDS_FLOATS (128 * LDW2 + NWAVES * RPW * 128)   // 16512 + 8192 = 24704 fl = 98816 B

__device__ __forceinline__ float wred64(float v) {
#pragma unroll
    for (int m = 1; m < 64; m <<= 1) v += __shfl_xor(v, m, 64);
    return v;
}

// z[r] += W2 * s[r]   (W2s row-major, stride LDW2; lane owns out channels cA,cB)
__device__ __forceinline__ void matvec_fwd(const float* __restrict__ W2s,
                                           const float* __restrict__ Srow,
                                           int cA, int cB,
                                           float (&za)[RPW], float (&zb)[RPW])
{
    const float* wra = W2s + cA * LDW2;
    const float* wrb = W2s + cB * LDW2;
#pragma unroll 4
    for (int j4 = 0; j4 < 32; ++j4) {
        const float wa0 = wra[4*j4+0], wa1 = wra[4*j4+1], wa2 = wra[4*j4+2], wa3 = wra[4*j4+3];
        const float wb0 = wrb[4*j4+0], wb1 = wrb[4*j4+1], wb2 = wrb[4*j4+2], wb3 = wrb[4*j4+3];
#pragma unroll
        for (int r = 0; r < RPW; ++r) {
            const float4 s4 = *(const float4*)(Srow + r * 128 + 4*j4);   // broadcast read
            za[r] = fmaf(wa0, s4.x, fmaf(wa1, s4.y, fmaf(wa2, s4.z, fmaf(wa3, s4.w, za[r]))));
            zb[r] = fmaf(wb0, s4.x, fmaf(wb1, s4.y, fmaf(wb2, s4.z, fmaf(wb3, s4.w, zb[r]))));
        }
    }
}

// z[r] += W2^T * s[r]  (column reads: W2s[i*LDW2 + c], stride-LDW2 b32 -> 2-way banks, free)
__device__ __forceinline__ void matvec_tr(const float* __restrict__ W2s,
                                          const float* __restrict__ Srow,
                                          int cA, int cB,
                                          float (&za)[RPW], float (&zb)[RPW])
{
    const float* wca = W2s + cA;
    const float* wcb = W2s + cB;
#pragma unroll 4
    for (int i4 = 0; i4 < 32; ++i4) {
        const float wa0 = wca[(4*i4+0)*LDW2], wa1 = wca[(4*i4+1)*LDW2],
                    wa2 = wca[(4*i4+2)*LDW2], wa3 = wca[(4*i4+3)*LDW2];
        const float wb0 = wcb[(4*i4+0)*LDW2], wb1 = wcb[(4*i4+1)*LDW2],
                    wb2 = wcb[(4*i4+2)*LDW2], wb3 = wcb[(4*i4+3)*LDW2];
#pragma unroll
        for (int r = 0; r < RPW; ++r) {
            const float4 s4 = *(const float4*)(Srow + r * 128 + 4*i4);   // broadcast read
            za[r] = fmaf(wa0, s4.x, fmaf(wa1, s4.y, fmaf(wa2, s4.z, fmaf(wa3, s4.w, za[r]))));
            zb[r] = fmaf(wb0, s4.x, fmaf(wb1, s4.y, fmaf(wb2, s4.z, fmaf(wb3, s4.w, zb[r]))));
        }
    }
}

extern "C" __global__ __launch_bounds__(NTHREADS, 2)
void lnn_kernel(const float* __restrict__ gx, const float* __restrict__ gW1,
                const float* __restrict__ gb1, const float* __restrict__ gW2,
                const float* __restrict__ gb2, const float* __restrict__ gW3,
                float* __restrict__ gout)
{
    extern __shared__ float lds[];
    float* W2s = lds;                  // [128][LDW2]
    float* Sst = lds + 128 * LDW2;     // [NWAVES][RPW][128] per-wave staging

    const int tid  = threadIdx.x;
    const int lane = tid & 63;
    const int wv   = tid >> 6;
    const int cA = lane, cB = lane + 64;

    for (int e = tid; e < 16384; e += NTHREADS) {
        W2s[(e >> 7) * LDW2 + (e & 127)] = gW2[e];
    }

    const float w1a0 = gW1[cA * 4 + 0], w1a1 = gW1[cA * 4 + 1],
                w1a2 = gW1[cA * 4 + 2], w1a3 = gW1[cA * 4 + 3];
    const float w1b0 = gW1[cB * 4 + 0], w1b1 = gW1[cB * 4 + 1],
                w1b2 = gW1[cB * 4 + 2], w1b3 = gW1[cB * 4 + 3];
    const float b1a = gb1[cA], b1b = gb1[cB];
    const float b2a = gb2[cA], b2b = gb2[cB];
    const float w3a = gW3[cA], w3b = gW3[cB];

    __syncthreads();   // W2 staged; Srow below is wave-private (no further barriers)

    float* Srow = Sst + wv * (RPW * 128);

#pragma unroll 1
    for (int it = 0; it < NITERS; ++it) {
        const int row0 = blockIdx.x * (NITERS * NWAVES * RPW) + it * (NWAVES * RPW) + wv * RPW;

        float p0[RPW], p1[RPW], q0[RPW], q1[RPW], v0[RPW], v1[RPW];
        float sw[RPW], pv[RPW], g0[RPW], X2[RPW], X3[RPW];

        // ---- layer 1 forward: p = softmax(W1 x + b1)
#pragma unroll
        for (int r = 0; r < RPW; ++r) {
            const float4 xr = ((const float4*)gx)[row0 + r];
            X2[r] = xr.z; X3[r] = xr.w;
            const float z1a = fmaf(w1a0, xr.x, fmaf(w1a1, xr.y, fmaf(w1a2, xr.z, fmaf(w1a3, xr.w, b1a))));
            const float z1b = fmaf(w1b0, xr.x, fmaf(w1b1, xr.y, fmaf(w1b2, xr.z, fmaf(w1b3, xr.w, b1b))));
            const float ea = __expf(z1a), eb = __expf(z1b);
            const float rs = 1.0f / wred64(ea + eb);
            p0[r] = ea * rs; p1[r] = eb * rs;
            Srow[r * 128 + cA] = p0[r];
            Srow[r * 128 + cB] = p1[r];
        }

        // ---- layer 2 forward: q = softmax(W2 p + b2); u = dL/dz2 = q*(w3 - s)
        float za[RPW], zb[RPW];
#pragma unroll
        for (int r = 0; r < RPW; ++r) { za[r] = b2a; zb[r] = b2b; }
        matvec_fwd(W2s, Srow, cA, cB, za, zb);
#pragma unroll
        for (int r = 0; r < RPW; ++r) {
            const float ea = __expf(za[r]), eb = __expf(zb[r]);
            const float rs = 1.0f / wred64(ea + eb);
            q0[r] = ea * rs; q1[r] = eb * rs;
            sw[r] = wred64(fmaf(w3a, q0[r], w3b * q1[r]));
            Srow[r * 128 + cA] = q0[r] * (w3a - sw[r]);
            Srow[r * 128 + cB] = q1[r] * (w3b - sw[r]);
        }

        // ---- backward: v = W2^T u ; gamma = p*(v - p.v) ; g0 = W1[:,0].gamma
#pragma unroll
        for (int r = 0; r < RPW; ++r) { za[r] = 0.f; zb[r] = 0.f; }
        matvec_tr(W2s, Srow, cA, cB, za, zb);
#pragma unroll
        for (int r = 0; r < RPW; ++r) {
            v0[r] = za[r]; v1[r] = zb[r];
            pv[r] = wred64(fmaf(p0[r], v0[r], p1[r] * v1[r]));
            g0[r] = wred64(fmaf(w1a0, p0[r] * (v0[r] - pv[r]), w1b0 * (p1[r] * (v1[r] - pv[r]))));
        }

        float h20[RPW], h21[RPW], h22[RPW], h23[RPW];
        float h30[RPW], h31[RPW], h32[RPW], h33[RPW];

        // ---- HVP with tangent t = W1[:,k] (per-lane: ta = W1[cA,k], tb = W1[cB,k])
        auto hvp = [&](float ta, float tb, float (&o0)[RPW], float (&o1)[RPW],
                       float (&o2)[RPW], float (&o3)[RPW]) {
            float pd0[RPW], pd1[RPW];
#pragma unroll
            for (int r = 0; r < RPW; ++r) {
                const float pi = wred64(fmaf(ta, p0[r], tb * p1[r]));
                pd0[r] = p0[r] * (ta - pi);
                pd1[r] = p1[r] * (tb - pi);
                Srow[r * 128 + cA] = pd0[r];
                Srow[r * 128 + cB] = pd1[r];
            }
            float zd0[RPW], zd1[RPW];
#pragma unroll
            for (int r = 0; r < RPW; ++r) { zd0[r] = 0.f; zd1[r] = 0.f; }
            matvec_fwd(W2s, Srow, cA, cB, zd0, zd1);     // zdot2 = W2 pdot
#pragma unroll
            for (int r = 0; r < RPW; ++r) {
                const float sg = wred64(fmaf(q0[r], zd0[r], q1[r] * zd1[r]));
                const float qd0 = q0[r] * (zd0[r] - sg);
                const float qd1 = q1[r] * (zd1[r] - sg);
                const float sd = wred64(fmaf(w3a, qd0, w3b * qd1));
                Srow[r * 128 + cA] = fmaf(qd0, w3a - sw[r], -(q0[r] * sd));  // udot
                Srow[r * 128 + cB] = fmaf(qd1, w3b - sw[r], -(q1[r] * sd));
            }
            float vd0[RPW], vd1[RPW];
#pragma unroll
            for (int r = 0; r < RPW; ++r) { vd0[r] = 0.f; vd1[r] = 0.f; }
            matvec_tr(W2s, Srow, cA, cB, vd0, vd1);      // vdot = W2^T udot
#pragma unroll
            for (int r = 0; r < RPW; ++r) {
                const float dpv = wred64(fmaf(pd0[r], v0[r],
                                     fmaf(pd1[r], v1[r],
                                     fmaf(p0[r], vd0[r], p1[r] * vd1[r]))));
                const float gd0 = fmaf(pd0[r], v0[r] - pv[r], p0[r] * (vd0[r] - dpv));
                const float gd1 = fmaf(pd1[r], v1[r] - pv[r], p1[r] * (vd1[r] - dpv));
                o0[r] = wred64(fmaf(w1a0, gd0, w1b0 * gd1));
                o1[r] = wred64(fmaf(w1a1, gd0, w1b1 * gd1));
                o2[r] = wred64(fmaf(w1a2, gd0, w1b2 * gd1));
                o3[r] = wred64(fmaf(w1a3, gd0, w1b3 * gd1));
            }
        };

        hvp(w1a2, w1b2, h20, h21, h22, h23);   // H[:,2]
        hvp(w1a3, w1b3, h30, h31, h32, h33);   // H[:,3]

        // ---- 2x2 solve + store (tqt passthrough is exact)
#pragma unroll
        for (int r = 0; r < RPW; ++r) {
            const float rhs0 = g0[r] - fmaf(h20[r], X2[r], h21[r] * X3[r]);  // H[2,0],H[2,1]
            const float rhs1 = g0[r] - fmaf(h30[r], X2[r], h31[r] * X3[r]);  // H[3,0],H[3,1]
            const float a = h22[r], b = h32[r], c = h23[r], d = h33[r];      // H22,H23,H32,H33
            const float det = fmaf(a, d, -(b * c));
            const float t0 = fmaf(d, rhs0, -(b * rhs1)) / det;
            const float t1 = fmaf(a, rhs1, -(c * rhs0)) / det;
            if (lane == 0) {
                ((float4*)gout)[row0 + r] = make_float4(X2[r], X3[r], t0, t1);
            }
        }
    }
}

extern "C" void kernel_launch(void* const* d_in, const int* in_sizes, int n_in,
                              void* d_out, int out_size, void* d_ws, size_t ws_size,
                              hipStream_t stream)
{
    const float* gx  = (const float*)d_in[0];
    const float* gW1 = (const float*)d_in[1];
    const float* gb1 = (const float*)d_in[2];
    const float* gW2 = (const float*)d_in[3];
    const float* gb2 = (const float*)d_in[4];
    const float* gW3 = (const float*)d_in[5];
    // d_in[6] = b3: unused (only derivatives of L are needed)
    float* gout = (float*)d_out;

    const size_t shmem = LDS_FLOATS * sizeof(float);   // 98816 B > 64 KB: opt-in
    (void)hipFuncSetAttribute((const void*)lnn_kernel,
                              hipFuncAttributeMaxDynamicSharedMemorySize, (int)shmem);
    lnn_kernel<<<NGRID, NTHREADS, shmem, stream>>>(gx, gW1, gb1, gW2, gb2, gW3, gout);
}

// Round 3
// 1382.541 us; speedup vs baseline: 1.5134x; 1.0955x over previous
//
#include <hip/hip_runtime.h>

// LNN_50302656971188 — batched grad + partial-Hessian of 2-layer softmax MLP + 2x2 solve.
// R3: kernel was LDS-pipe saturated (model: 31.6k LDS cyc/batch ~= wall). Fix:
//  - s-vectors broadcast via v_readlane (VALU->SGPR), never staged in LDS
//  - reductions via DPP (row_shr/bcast) instead of __shfl_xor (ds_swizzle)
//  - weights pre-paired {W[c][j],W[c+64][j]} float2 in LDS, fwd + transpose copies
//  - two HVP tangents fused so weight reads amortize 2x
//  - 2x2 solve in fp64 (cheap; protects absmax margin)

#define RPW 8
#define NWAVES 8
#define NTHREADS 512
#define NGRID 256
#define NITERS 16      // 256 blocks * 8 waves * 8 rows * 16 = 262144
#define WSTRIDE 65     // float2 per j-row (64 + 1 pad)
#define LDS_BYTES (2 * 128 * WSTRIDE * 8)   // 133120 B

typedef float v2f __attribute__((ext_vector_type(2)));

__device__ __forceinline__ float rlane(float v, int l) {
    return __int_as_float(__builtin_amdgcn_readlane(__float_as_int(v), l));
}

// full-wave (64) sum reduction, all-VALU (DPP), result uniform (SGPR-resident)
__device__ __forceinline__ float dppred(float x) {
    x += __int_as_float(__builtin_amdgcn_update_dpp(0, __float_as_int(x), 0x111, 0xf, 0xf, true)); // row_shr:1
    x += __int_as_float(__builtin_amdgcn_update_dpp(0, __float_as_int(x), 0x112, 0xf, 0xf, true)); // row_shr:2
    x += __int_as_float(__builtin_amdgcn_update_dpp(0, __float_as_int(x), 0x114, 0xf, 0xf, true)); // row_shr:4
    x += __int_as_float(__builtin_amdgcn_update_dpp(0, __float_as_int(x), 0x118, 0xf, 0xf, true)); // row_shr:8
    x += __int_as_float(__builtin_amdgcn_update_dpp(0, __float_as_int(x), 0x142, 0xa, 0xf, true)); // bcast15
    x += __int_as_float(__builtin_amdgcn_update_dpp(0, __float_as_int(x), 0x143, 0xc, 0xf, true)); // bcast31
    return rlane(x, 63);   // lane 63 holds the total
}

// acc[r] += W * s[r]; W pre-paired: Wb[j*WSTRIDE + lane] = {W[lane][j], W[lane+64][j]}
// s-vector distributed: s0[r] lane j holds s_j (j<64), s1[r] lane j holds s_{j+64}
__device__ __forceinline__ void mv1(const v2f* __restrict__ Wb, int lane,
                                    const float (&s0)[RPW], const float (&s1)[RPW],
                                    v2f (&acc)[RPW])
{
#pragma unroll 1
    for (int j = 0; j < 64; j += 4) {
#pragma unroll
        for (int u = 0; u < 4; ++u) {
            const v2f w = Wb[(j + u) * WSTRIDE + lane];
#pragma unroll
            for (int r = 0; r < RPW; ++r) {
                const float s = rlane(s0[r], j + u);
                acc[r] = __builtin_elementwise_fma(w, (v2f){s, s}, acc[r]);
            }
        }
    }
#pragma unroll 1
    for (int j = 0; j < 64; j += 4) {
#pragma unroll
        for (int u = 0; u < 4; ++u) {
            const v2f w = Wb[(64 + j + u) * WSTRIDE + lane];
#pragma unroll
            for (int r = 0; r < RPW; ++r) {
                const float s = rlane(s1[r], j + u);
                acc[r] = __builtin_elementwise_fma(w, (v2f){s, s}, acc[r]);
            }
        }
    }
}

// dual: two s-vectors share each weight read (HVP tangent fusion)
__device__ __forceinline__ void mv2(const v2f* __restrict__ Wb, int lane,
                                    const float (&a0)[RPW], const float (&a1)[RPW],
                                    const float (&b0)[RPW], const float (&b1)[RPW],
                                    v2f (&accA)[RPW], v2f (&accB)[RPW])
{
#pragma unroll 1
    for (int j = 0; j < 64; j += 4) {
#pragma unroll
        for (int u = 0; u < 4; ++u) {
            const v2f w = Wb[(j + u) * WSTRIDE + lane];
#pragma unroll
            for (int r = 0; r < RPW; ++r) {
                const float sa = rlane(a0[r], j + u);
                const float sb = rlane(b0[r], j + u);
                accA[r] = __builtin_elementwise_fma(w, (v2f){sa, sa}, accA[r]);
                accB[r] = __builtin_elementwise_fma(w, (v2f){sb, sb}, accB[r]);
            }
        }
    }
#pragma unroll 1
    for (int j = 0; j < 64; j += 4) {
#pragma unroll
        for (int u = 0; u < 4; ++u) {
            const v2f w = Wb[(64 + j + u) * WSTRIDE + lane];
#pragma unroll
            for (int r = 0; r < RPW; ++r) {
                const float sa = rlane(a1[r], j + u);
                const float sb = rlane(b1[r], j + u);
                accA[r] = __builtin_elementwise_fma(w, (v2f){sa, sa}, accA[r]);
                accB[r] = __builtin_elementwise_fma(w, (v2f){sb, sb}, accB[r]);
            }
        }
    }
}

extern "C" __global__ __launch_bounds__(NTHREADS, 2)
void lnn_kernel(const float* __restrict__ gx, const float* __restrict__ gW1,
                const float* __restrict__ gb1, const float* __restrict__ gW2,
                const float* __restrict__ gb2, const float* __restrict__ gW3,
                float* __restrict__ gout)
{
    extern __shared__ float lds[];
    v2f* Wp  = (v2f*)lds;                      // fwd: Wp[j][l]  = {W[l][j],  W[l+64][j]}
    v2f* Wtp = Wp + 128 * WSTRIDE;             // tr:  Wtp[i][l] = {W[i][l],  W[i][l+64]}

    const int tid  = threadIdx.x;
    const int lane = tid & 63;
    const int wv   = tid >> 6;

    for (int e = tid; e < 16384; e += NTHREADS) {
        const int i = e >> 7, j = e & 127;
        const float w = gW2[e];
        ((float*)Wp)[(j * WSTRIDE + (i & 63)) * 2 + (i >> 6)] = w;
        ((float*)Wtp)[(i * WSTRIDE + (j & 63)) * 2 + (j >> 6)] = w;
    }

    const int cA = lane, cB = lane + 64;
    const float w1a0 = gW1[cA * 4 + 0], w1a1 = gW1[cA * 4 + 1],
                w1a2 = gW1[cA * 4 + 2], w1a3 = gW1[cA * 4 + 3];
    const float w1b0 = gW1[cB * 4 + 0], w1b1 = gW1[cB * 4 + 1],
                w1b2 = gW1[cB * 4 + 2], w1b3 = gW1[cB * 4 + 3];
    const float b1a = gb1[cA], b1b = gb1[cB];
    const float b2a = gb2[cA], b2b = gb2[cB];
    const float w3a = gW3[cA], w3b = gW3[cB];

    __syncthreads();   // weights staged; no further barriers

#pragma unroll 1
    for (int it = 0; it < NITERS; ++it) {
        const int row0 = blockIdx.x * (NITERS * NWAVES * RPW) + it * (NWAVES * RPW) + wv * RPW;

        float p0[RPW], p1[RPW], q0[RPW], q1[RPW], v0[RPW], v1[RPW];
        float X2[RPW], X3[RPW];
        float sw[RPW], pv[RPW], g0[RPW];

        // ---- layer 1: p = softmax(W1 x + b1)
#pragma unroll
        for (int r = 0; r < RPW; ++r) {
            const float4 xr = ((const float4*)gx)[row0 + r];
            X2[r] = xr.z; X3[r] = xr.w;
            const float z1a = fmaf(w1a0, xr.x, fmaf(w1a1, xr.y, fmaf(w1a2, xr.z, fmaf(w1a3, xr.w, b1a))));
            const float z1b = fmaf(w1b0, xr.x, fmaf(w1b1, xr.y, fmaf(w1b2, xr.z, fmaf(w1b3, xr.w, b1b))));
            const float ea = __expf(z1a), eb = __expf(z1b);
            const float rs = 1.0f / dppred(ea + eb);
            p0[r] = ea * rs; p1[r] = eb * rs;
        }

        // ---- layer 2 forward: z = W2 p + b2 ; q = softmax(z); u = q*(w3 - s)
        v2f acc[RPW];
#pragma unroll
        for (int r = 0; r < RPW; ++r) acc[r] = (v2f){b2a, b2b};
        mv1(Wp, lane, p0, p1, acc);
        float u0[RPW], u1[RPW];
#pragma unroll
        for (int r = 0; r < RPW; ++r) {
            const float ea = __expf(acc[r].x), eb = __expf(acc[r].y);
            const float rs = 1.0f / dppred(ea + eb);
            q0[r] = ea * rs; q1[r] = eb * rs;
            sw[r] = dppred(fmaf(w3a, q0[r], w3b * q1[r]));
            u0[r] = q0[r] * (w3a - sw[r]);
            u1[r] = q1[r] * (w3b - sw[r]);
        }

        // ---- backward: v = W2^T u ; pv = p.v ; g0 = W1[:,0] . (p*(v-pv))
#pragma unroll
        for (int r = 0; r < RPW; ++r) acc[r] = (v2f){0.f, 0.f};
        mv1(Wtp, lane, u0, u1, acc);
#pragma unroll
        for (int r = 0; r < RPW; ++r) {
            v0[r] = acc[r].x; v1[r] = acc[r].y;
            pv[r] = dppred(fmaf(p0[r], v0[r], p1[r] * v1[r]));
            g0[r] = dppred(fmaf(w1a0, p0[r] * (v0[r] - pv[r]), w1b0 * (p1[r] * (v1[r] - pv[r]))));
        }

        // ---- dual HVP: tangents t2 = W1[:,2], t3 = W1[:,3]
        float pd20[RPW], pd21[RPW], pd30[RPW], pd31[RPW];
#pragma unroll
        for (int r = 0; r < RPW; ++r) {
            const float pi2 = dppred(fmaf(w1a2, p0[r], w1b2 * p1[r]));
            const float pi3 = dppred(fmaf(w1a3, p0[r], w1b3 * p1[r]));
            pd20[r] = p0[r] * (w1a2 - pi2); pd21[r] = p1[r] * (w1b2 - pi2);
            pd30[r] = p0[r] * (w1a3 - pi3); pd31[r] = p1[r] * (w1b3 - pi3);
        }
        v2f accd2[RPW], accd3[RPW];
#pragma unroll
        for (int r = 0; r < RPW; ++r) { accd2[r] = (v2f){0.f, 0.f}; accd3[r] = (v2f){0.f, 0.f}; }
        mv2(Wp, lane, pd20, pd21, pd30, pd31, accd2, accd3);   // zdot = W2 pdot

        float ud20[RPW], ud21[RPW], ud30[RPW], ud31[RPW];
#pragma unroll
        for (int r = 0; r < RPW; ++r) {
            const float zd20 = accd2[r].x, zd21 = accd2[r].y;
            const float zd30 = accd3[r].x, zd31 = accd3[r].y;
            const float sg2 = dppred(fmaf(q0[r], zd20, q1[r] * zd21));
            const float sg3 = dppred(fmaf(q0[r], zd30, q1[r] * zd31));
            const float qd20 = q0[r] * (zd20 - sg2), qd21 = q1[r] * (zd21 - sg2);
            const float qd30 = q0[r] * (zd30 - sg3), qd31 = q1[r] * (zd31 - sg3);
            const float sd2 = dppred(fmaf(w3a, qd20, w3b * qd21));
            const float sd3 = dppred(fmaf(w3a, qd30, w3b * qd31));
            ud20[r] = fmaf(qd20, w3a - sw[r], -(q0[r] * sd2));
            ud21[r] = fmaf(qd21, w3b - sw[r], -(q1[r] * sd2));
            ud30[r] = fmaf(qd30, w3a - sw[r], -(q0[r] * sd3));
            ud31[r] = fmaf(qd31, w3b - sw[r], -(q1[r] * sd3));
        }
#pragma unroll
        for (int r = 0; r < RPW; ++r) { accd2[r] = (v2f){0.f, 0.f}; accd3[r] = (v2f){0.f, 0.f}; }
        mv2(Wtp, lane, ud20, ud21, ud30, ud31, accd2, accd3);  // vdot = W2^T udot

#pragma unroll
        for (int r = 0; r < RPW; ++r) {
            const float vd20 = accd2[r].x, vd21 = accd2[r].y;
            const float vd30 = accd3[r].x, vd31 = accd3[r].y;
            const float dpv2 = dppred(fmaf(pd20[r], v0[r], fmaf(pd21[r], v1[r],
                               fmaf(p0[r], vd20, p1[r] * vd21))));
            const float dpv3 = dppred(fmaf(pd30[r], v0[r], fmaf(pd31[r], v1[r],
                               fmaf(p0[r], vd30, p1[r] * vd31))));
            const float gd20 = fmaf(pd20[r], v0[r] - pv[r], p0[r] * (vd20 - dpv2));
            const float gd21 = fmaf(pd21[r], v1[r] - pv[r], p1[r] * (vd21 - dpv2));
            const float gd30 = fmaf(pd30[r], v0[r] - pv[r], p0[r] * (vd30 - dpv3));
            const float gd31 = fmaf(pd31[r], v1[r] - pv[r], p1[r] * (vd31 - dpv3));
            const float h20 = dppred(fmaf(w1a0, gd20, w1b0 * gd21));
            const float h21 = dppred(fmaf(w1a1, gd20, w1b1 * gd21));
            const float h22 = dppred(fmaf(w1a2, gd20, w1b2 * gd21));
            const float h23 = dppred(fmaf(w1a3, gd20, w1b3 * gd21));
            const float h30 = dppred(fmaf(w1a0, gd30, w1b0 * gd31));
            const float h31 = dppred(fmaf(w1a1, gd30, w1b1 * gd31));
            const float h32 = dppred(fmaf(w1a2, gd30, w1b2 * gd31));
            const float h33 = dppred(fmaf(w1a3, gd30, w1b3 * gd31));

            // ---- 2x2 solve in fp64 (cheap; det cancellation is the error amplifier)
            const double rhs0 = (double)g0[r] - ((double)h20 * (double)X2[r] + (double)h21 * (double)X3[r]);
            const double rhs1 = (double)g0[r] - ((double)h30 * (double)X2[r] + (double)h31 * (double)X3[r]);
            const double a = (double)h22, b = (double)h32, c = (double)h23, d = (double)h33;
            const double det = a * d - b * c;
            const float t0 = (float)((d * rhs0 - b * rhs1) / det);
            const float t1 = (float)((a * rhs1 - c * rhs0) / det);
            if (lane == 0) {
                ((float4*)gout)[row0 + r] = make_float4(X2[r], X3[r], t0, t1);
            }
        }
    }
}

extern "C" void kernel_launch(void* const* d_in, const int* in_sizes, int n_in,
                              void* d_out, int out_size, void* d_ws, size_t ws_size,
                              hipStream_t stream)
{
    const float* gx  = (const float*)d_in[0];
    const float* gW1 = (const float*)d_in[1];
    const float* gb1 = (const float*)d_in[2];
    const float* gW2 = (const float*)d_in[3];
    const float* gb2 = (const float*)d_in[4];
    const float* gW3 = (const float*)d_in[5];
    float* gout = (float*)d_out;

    (void)hipFuncSetAttribute((const void*)lnn_kernel,
                              hipFuncAttributeMaxDynamicSharedMemorySize, LDS_BYTES);
    lnn_kernel<<<NGRID, NTHREADS, LDS_BYTES, stream>>>(gx, gW1, gb1, gW2, gb2, gW3, gout);
}

// Round 4
// 1377.274 us; speedup vs baseline: 1.5191x; 1.0038x over previous
//
#include <hip/hip_runtime.h>

// LNN_50302656971188 — batched grad + partial-Hessian of 2-layer softmax MLP + 2x2 solve.
// R4: R3 was VALU-issue bound (86% busy) but ~half the issue slots were v_mov bloat
// from building (v2f){s,s} operands for packed FMA. Fix: scalar accumulators +
// v_fma_f32 reading the readlane'd SGPR directly (VOP3 allows 1 SGPR operand).
// Arithmetic order bit-identical to R3 (absmax 5120 must not move).

#define RPW 8
#define NWAVES 8
#define NTHREADS 512
#define NGRID 256
#define NITERS 16      // 256 blocks * 8 waves * 8 rows * 16 = 262144
#define WSTRIDE 65     // float2 per j-row (64 + 1 pad)
#define LDS_BYTES (2 * 128 * WSTRIDE * 8)   // 133120 B

typedef float v2f __attribute__((ext_vector_type(2)));

__device__ __forceinline__ float rlane(float v, int l) {
    return __int_as_float(__builtin_amdgcn_readlane(__float_as_int(v), l));
}

// full-wave (64) sum reduction, all-VALU (DPP), result uniform
__device__ __forceinline__ float dppred(float x) {
    x += __int_as_float(__builtin_amdgcn_update_dpp(0, __float_as_int(x), 0x111, 0xf, 0xf, true)); // row_shr:1
    x += __int_as_float(__builtin_amdgcn_update_dpp(0, __float_as_int(x), 0x112, 0xf, 0xf, true)); // row_shr:2
    x += __int_as_float(__builtin_amdgcn_update_dpp(0, __float_as_int(x), 0x114, 0xf, 0xf, true)); // row_shr:4
    x += __int_as_float(__builtin_amdgcn_update_dpp(0, __float_as_int(x), 0x118, 0xf, 0xf, true)); // row_shr:8
    x += __int_as_float(__builtin_amdgcn_update_dpp(0, __float_as_int(x), 0x142, 0xa, 0xf, true)); // bcast15
    x += __int_as_float(__builtin_amdgcn_update_dpp(0, __float_as_int(x), 0x143, 0xc, 0xf, true)); // bcast31
    return rlane(x, 63);
}

// acc{a,b}[r] += W * s[r]; W pre-paired: Wb[j*WSTRIDE + lane] = {W[lane][j], W[lane+64][j]}
// s distributed: s0[r] lane j holds s_j (j<64), s1[r] lane j holds s_{j+64}
__device__ __forceinline__ void mv1(const v2f* __restrict__ Wb, int lane,
                                    const float (&s0)[RPW], const float (&s1)[RPW],
                                    float (&za)[RPW], float (&zb)[RPW])
{
    const v2f* wp = Wb + lane;
#pragma unroll 4
    for (int j = 0; j < 64; ++j) {
        const v2f w = wp[j * WSTRIDE];
#pragma unroll
        for (int r = 0; r < RPW; ++r) {
            const float s = rlane(s0[r], j);        // SGPR
            za[r] = fmaf(w.x, s, za[r]);            // v_fma_f32 v,v,s,v — no movs
            zb[r] = fmaf(w.y, s, zb[r]);
        }
    }
#pragma unroll 4
    for (int j = 0; j < 64; ++j) {
        const v2f w = wp[(64 + j) * WSTRIDE];
#pragma unroll
        for (int r = 0; r < RPW; ++r) {
            const float s = rlane(s1[r], j);
            za[r] = fmaf(w.x, s, za[r]);
            zb[r] = fmaf(w.y, s, zb[r]);
        }
    }
}

// dual: two s-vectors share each weight read (HVP tangent fusion)
__device__ __forceinline__ void mv2(const v2f* __restrict__ Wb, int lane,
                                    const float (&a0)[RPW], const float (&a1)[RPW],
                                    const float (&b0)[RPW], const float (&b1)[RPW],
                                    float (&zAa)[RPW], float (&zAb)[RPW],
                                    float (&zBa)[RPW], float (&zBb)[RPW])
{
    const v2f* wp = Wb + lane;
#pragma unroll 4
    for (int j = 0; j < 64; ++j) {
        const v2f w = wp[j * WSTRIDE];
#pragma unroll
        for (int r = 0; r < RPW; ++r) {
            const float sa = rlane(a0[r], j);
            const float sb = rlane(b0[r], j);
            zAa[r] = fmaf(w.x, sa, zAa[r]);
            zAb[r] = fmaf(w.y, sa, zAb[r]);
            zBa[r] = fmaf(w.x, sb, zBa[r]);
            zBb[r] = fmaf(w.y, sb, zBb[r]);
        }
    }
#pragma unroll 4
    for (int j = 0; j < 64; ++j) {
        const v2f w = wp[(64 + j) * WSTRIDE];
#pragma unroll
        for (int r = 0; r < RPW; ++r) {
            const float sa = rlane(a1[r], j);
            const float sb = rlane(b1[r], j);
            zAa[r] = fmaf(w.x, sa, zAa[r]);
            zAb[r] = fmaf(w.y, sa, zAb[r]);
            zBa[r] = fmaf(w.x, sb, zBa[r]);
            zBb[r] = fmaf(w.y, sb, zBb[r]);
        }
    }
}

extern "C" __global__ __launch_bounds__(NTHREADS, 2)
void lnn_kernel(const float* __restrict__ gx, const float* __restrict__ gW1,
                const float* __restrict__ gb1, const float* __restrict__ gW2,
                const float* __restrict__ gb2, const float* __restrict__ gW3,
                float* __restrict__ gout)
{
    extern __shared__ float lds[];
    v2f* Wp  = (v2f*)lds;                      // fwd: Wp[j][l]  = {W[l][j],  W[l+64][j]}
    v2f* Wtp = Wp + 128 * WSTRIDE;             // tr:  Wtp[i][l] = {W[i][l],  W[i][l+64]}

    const int tid  = threadIdx.x;
    const int lane = tid & 63;
    const int wv   = tid >> 6;

    for (int e = tid; e < 16384; e += NTHREADS) {
        const int i = e >> 7, j = e & 127;
        const float w = gW2[e];
        ((float*)Wp)[(j * WSTRIDE + (i & 63)) * 2 + (i >> 6)] = w;
        ((float*)Wtp)[(i * WSTRIDE + (j & 63)) * 2 + (j >> 6)] = w;
    }

    const int cA = lane, cB = lane + 64;
    const float w1a0 = gW1[cA * 4 + 0], w1a1 = gW1[cA * 4 + 1],
                w1a2 = gW1[cA * 4 + 2], w1a3 = gW1[cA * 4 + 3];
    const float w1b0 = gW1[cB * 4 + 0], w1b1 = gW1[cB * 4 + 1],
                w1b2 = gW1[cB * 4 + 2], w1b3 = gW1[cB * 4 + 3];
    const float b1a = gb1[cA], b1b = gb1[cB];
    const float b2a = gb2[cA], b2b = gb2[cB];
    const float w3a = gW3[cA], w3b = gW3[cB];

    __syncthreads();   // weights staged; no further barriers

#pragma unroll 1
    for (int it = 0; it < NITERS; ++it) {
        const int row0 = blockIdx.x * (NITERS * NWAVES * RPW) + it * (NWAVES * RPW) + wv * RPW;

        float p0[RPW], p1[RPW], q0[RPW], q1[RPW], v0[RPW], v1[RPW];
        float X2[RPW], X3[RPW];
        float sw[RPW], pv[RPW], g0[RPW];

        // ---- layer 1: p = softmax(W1 x + b1)
#pragma unroll
        for (int r = 0; r < RPW; ++r) {
            const float4 xr = ((const float4*)gx)[row0 + r];
            X2[r] = xr.z; X3[r] = xr.w;
            const float z1a = fmaf(w1a0, xr.x, fmaf(w1a1, xr.y, fmaf(w1a2, xr.z, fmaf(w1a3, xr.w, b1a))));
            const float z1b = fmaf(w1b0, xr.x, fmaf(w1b1, xr.y, fmaf(w1b2, xr.z, fmaf(w1b3, xr.w, b1b))));
            const float ea = __expf(z1a), eb = __expf(z1b);
            const float rs = 1.0f / dppred(ea + eb);
            p0[r] = ea * rs; p1[r] = eb * rs;
        }

        // ---- layer 2 forward: z = W2 p + b2 ; q = softmax(z); u = q*(w3 - s)
        float zfa[RPW], zfb[RPW];
#pragma unroll
        for (int r = 0; r < RPW; ++r) { zfa[r] = b2a; zfb[r] = b2b; }
        mv1(Wp, lane, p0, p1, zfa, zfb);
        float u0[RPW], u1[RPW];
#pragma unroll
        for (int r = 0; r < RPW; ++r) {
            const float ea = __expf(zfa[r]), eb = __expf(zfb[r]);
            const float rs = 1.0f / dppred(ea + eb);
            q0[r] = ea * rs; q1[r] = eb * rs;
            sw[r] = dppred(fmaf(w3a, q0[r], w3b * q1[r]));
            u0[r] = q0[r] * (w3a - sw[r]);
            u1[r] = q1[r] * (w3b - sw[r]);
        }

        // ---- backward: v = W2^T u ; pv = p.v ; g0 = W1[:,0] . (p*(v-pv))
#pragma unroll
        for (int r = 0; r < RPW; ++r) { zfa[r] = 0.f; zfb[r] = 0.f; }
        mv1(Wtp, lane, u0, u1, zfa, zfb);
#pragma unroll
        for (int r = 0; r < RPW; ++r) {
            v0[r] = zfa[r]; v1[r] = zfb[r];
            pv[r] = dppred(fmaf(p0[r], v0[r], p1[r] * v1[r]));
            g0[r] = dppred(fmaf(w1a0, p0[r] * (v0[r] - pv[r]), w1b0 * (p1[r] * (v1[r] - pv[r]))));
        }

        // ---- dual HVP: tangents t2 = W1[:,2], t3 = W1[:,3]
        float pd20[RPW], pd21[RPW], pd30[RPW], pd31[RPW];
#pragma unroll
        for (int r = 0; r < RPW; ++r) {
            const float pi2 = dppred(fmaf(w1a2, p0[r], w1b2 * p1[r]));
            const float pi3 = dppred(fmaf(w1a3, p0[r], w1b3 * p1[r]));
            pd20[r] = p0[r] * (w1a2 - pi2); pd21[r] = p1[r] * (w1b2 - pi2);
            pd30[r] = p0[r] * (w1a3 - pi3); pd31[r] = p1[r] * (w1b3 - pi3);
        }
        float z2a[RPW], z2b[RPW], z3a[RPW], z3b[RPW];
#pragma unroll
        for (int r = 0; r < RPW; ++r) { z2a[r] = 0.f; z2b[r] = 0.f; z3a[r] = 0.f; z3b[r] = 0.f; }
        mv2(Wp, lane, pd20, pd21, pd30, pd31, z2a, z2b, z3a, z3b);   // zdot = W2 pdot

        float ud20[RPW], ud21[RPW], ud30[RPW], ud31[RPW];
#pragma unroll
        for (int r = 0; r < RPW; ++r) {
            const float zd20 = z2a[r], zd21 = z2b[r];
            const float zd30 = z3a[r], zd31 = z3b[r];
            const float sg2 = dppred(fmaf(q0[r], zd20, q1[r] * zd21));
            const float sg3 = dppred(fmaf(q0[r], zd30, q1[r] * zd31));
            const float qd20 = q0[r] * (zd20 - sg2), qd21 = q1[r] * (zd21 - sg2);
            const float qd30 = q0[r] * (zd30 - sg3), qd31 = q1[r] * (zd31 - sg3);
            const float sd2 = dppred(fmaf(w3a, qd20, w3b * qd21));
            const float sd3 = dppred(fmaf(w3a, qd30, w3b * qd31));
            ud20[r] = fmaf(qd20, w3a - sw[r], -(q0[r] * sd2));
            ud21[r] = fmaf(qd21, w3b - sw[r], -(q1[r] * sd2));
            ud30[r] = fmaf(qd30, w3a - sw[r], -(q0[r] * sd3));
            ud31[r] = fmaf(qd31, w3b - sw[r], -(q1[r] * sd3));
        }
#pragma unroll
        for (int r = 0; r < RPW; ++r) { z2a[r] = 0.f; z2b[r] = 0.f; z3a[r] = 0.f; z3b[r] = 0.f; }
        mv2(Wtp, lane, ud20, ud21, ud30, ud31, z2a, z2b, z3a, z3b);  // vdot = W2^T udot

#pragma unroll
        for (int r = 0; r < RPW; ++r) {
            const float vd20 = z2a[r], vd21 = z2b[r];
            const float vd30 = z3a[r], vd31 = z3b[r];
            const float dpv2 = dppred(fmaf(pd20[r], v0[r], fmaf(pd21[r], v1[r],
                               fmaf(p0[r], vd20, p1[r] * vd21))));
            const float dpv3 = dppred(fmaf(pd30[r], v0[r], fmaf(pd31[r], v1[r],
                               fmaf(p0[r], vd30, p1[r] * vd31))));
            const float gd20 = fmaf(pd20[r], v0[r] - pv[r], p0[r] * (vd20 - dpv2));
            const float gd21 = fmaf(pd21[r], v1[r] - pv[r], p1[r] * (vd21 - dpv2));
            const float gd30 = fmaf(pd30[r], v0[r] - pv[r], p0[r] * (vd30 - dpv3));
            const float gd31 = fmaf(pd31[r], v1[r] - pv[r], p1[r] * (vd31 - dpv3));
            const float h20 = dppred(fmaf(w1a0, gd20, w1b0 * gd21));
            const float h21 = dppred(fmaf(w1a1, gd20, w1b1 * gd21));
            const float h22 = dppred(fmaf(w1a2, gd20, w1b2 * gd21));
            const float h23 = dppred(fmaf(w1a3, gd20, w1b3 * gd21));
            const float h30 = dppred(fmaf(w1a0, gd30, w1b0 * gd31));
            const float h31 = dppred(fmaf(w1a1, gd30, w1b1 * gd31));
            const float h32 = dppred(fmaf(w1a2, gd30, w1b2 * gd31));
            const float h33 = dppred(fmaf(w1a3, gd30, w1b3 * gd31));

            // ---- 2x2 solve in fp64 (cheap; det cancellation is the error amplifier)
            const double rhs0 = (double)g0[r] - ((double)h20 * (double)X2[r] + (double)h21 * (double)X3[r]);
            const double rhs1 = (double)g0[r] - ((double)h30 * (double)X2[r] + (double)h31 * (double)X3[r]);
            const double a = (double)h22, b = (double)h32, c = (double)h23, d = (double)h33;
            const double det = a * d - b * c;
            const float t0 = (float)((d * rhs0 - b * rhs1) / det);
            const float t1 = (float)((a * rhs1 - c * rhs0) / det);
            if (lane == 0) {
                ((float4*)gout)[row0 + r] = make_float4(X2[r], X3[r], t0, t1);
            }
        }
    }
}

extern "C" void kernel_launch(void* const* d_in, const int* in_sizes, int n_in,
                              void* d_out, int out_size, void* d_ws, size_t ws_size,
                              hipStream_t stream)
{
    const float* gx  = (const float*)d_in[0];
    const float* gW1 = (const float*)d_in[1];
    const float* gb1 = (const float*)d_in[2];
    const float* gW2 = (const float*)d_in[3];
    const float* gb2 = (const float*)d_in[4];
    const float* gW3 = (const float*)d_in[5];
    float* gout = (float*)d_out;

    (void)hipFuncSetAttribute((const void*)lnn_kernel,
                              hipFuncAttributeMaxDynamicSharedMemorySize, LDS_BYTES);
    lnn_kernel<<<NGRID, NTHREADS, LDS_BYTES, stream>>>(gx, gW1, gb1, gW2, gb2, gW3, gout);
}